// Round 6
// baseline (4906.861 us; speedup 1.0000x reference)
//
#include <hip/hip_runtime.h>
#include <hip/hip_bf16.h>
#include <stdint.h>
#include <stddef.h>

// ---- problem constants ----
#define NB 8
#define TT 256
#define IDIM 256
#define HH 512
#define VV 256
#define DD 32
#define NDEC 64
#define NTHINK 16
#define HCB 8
#define HSL 64
#define NTHR 1024

// ---- ws layout (bytes), all 8B aligned ----
#define CTR_OFF   0u
#define FLG_OFF   1024u
#define HNEW_OFF  4096u      // 2*8*512 f64 = 65,536
#define YP_OFF    69632u     // 2*8*8*256 f64 = 262,144
#define DLY_OFF   331776u    // 512*512 u8 = 262,144 -> end 593,920

// ---------------- agent-scope atomic helpers ----------
__device__ __forceinline__ void astd(double* p, double v){
  __hip_atomic_store(p, v, __ATOMIC_RELAXED, __HIP_MEMORY_SCOPE_AGENT);
}
__device__ __forceinline__ double aldd(double* p){
  return __hip_atomic_load(p, __ATOMIC_RELAXED, __HIP_MEMORY_SCOPE_AGENT);
}
__device__ __forceinline__ void astu(uint32_t* p, uint32_t v){
  __hip_atomic_store(p, v, __ATOMIC_RELAXED, __HIP_MEMORY_SCOPE_AGENT);
}
__device__ __forceinline__ uint32_t aldu(uint32_t* p){
  return __hip_atomic_load(p, __ATOMIC_RELAXED, __HIP_MEMORY_SCOPE_AGENT);
}

// ---------------- threefry2x32 (matches jax) ----------------
__device__ __forceinline__ void tfr(uint32_t &x0, uint32_t &x1, int r){
  x0 += x1; x1 = (x1 << r) | (x1 >> (32 - r)); x1 ^= x0;
}
__device__ __forceinline__ void threefry(uint32_t k0, uint32_t k1,
                                         uint32_t c0, uint32_t c1,
                                         uint32_t &o0, uint32_t &o1){
  const uint32_t k2 = k0 ^ k1 ^ 0x1BD11BDAu;
  uint32_t x0 = c0 + k0, x1 = c1 + k1;
  tfr(x0,x1,13); tfr(x0,x1,15); tfr(x0,x1,26); tfr(x0,x1,6);
  x0 += k1; x1 += k2 + 1u;
  tfr(x0,x1,17); tfr(x0,x1,29); tfr(x0,x1,16); tfr(x0,x1,24);
  x0 += k2; x1 += k0 + 2u;
  tfr(x0,x1,13); tfr(x0,x1,15); tfr(x0,x1,26); tfr(x0,x1,6);
  x0 += k0; x1 += k1 + 3u;
  tfr(x0,x1,17); tfr(x0,x1,29); tfr(x0,x1,16); tfr(x0,x1,24);
  x0 += k1; x1 += k2 + 4u;
  tfr(x0,x1,13); tfr(x0,x1,15); tfr(x0,x1,26); tfr(x0,x1,6);
  x0 += k2; x1 += k0 + 5u;
  o0 = x0; o1 = x1;
}
// jax partitionable threefry random_bits (32-bit): counter (0, i), bits = o0^o1
__device__ __forceinline__ uint32_t pbits(uint32_t k0, uint32_t k1, uint32_t i){
  uint32_t o0, o1; threefry(k0, k1, 0u, i, o0, o1);
  return o0 ^ o1;
}
__device__ __forceinline__ float bits_to_unit(uint32_t bits){
  return __uint_as_float((bits >> 9) | 0x3F800000u) - 1.0f;
}

// ---------------- kernel A: credit argmax -> delay table (0 = dead) --------
__global__ __launch_bounds__(256) void delays_kernel(
    const float* __restrict__ tau, unsigned char* __restrict__ dl)
{
  const int e = blockIdx.x * 256 + threadIdx.x;
  if (e >= HH*HH) return;
  uint32_t kc0, kc1; threefry(0u, 42u, 0u, 0u, kc0, kc1);  // fold_in(key(42),0)
  const float tcf = fminf(fmaxf(tau[e], 1.0f), 32.0f);
  const double tc = (double)tcf;
  double best = -1.0e300; int am = 0;
  for (int d = 0; d <= DD; ++d){
    const uint32_t f = (uint32_t)d * (uint32_t)(HH*HH) + (uint32_t)e;
    const double u = (double)bits_to_unit(pbits(kc0, kc1, f));
    const double raw = 1.0 / sqrt(1.0 + fabs((double)d - tc));
    const double pert = log(raw + 1e-8) - log(-log(u + 1e-8) + 1e-8);
    if (pert > best){ best = pert; am = d; }
  }
  dl[e] = (unsigned char)am;
}

// ---------------- kernel B: the sequential RNN (f64 trajectory) -------------
__global__ __launch_bounds__(NTHR) void seq_kernel(
    const float* __restrict__ x, const int* __restrict__ lengths,
    const float* __restrict__ aff_w, const float* __restrict__ aff_b,
    const float* __restrict__ eff_w, const float* __restrict__ eff_b,
    const float* __restrict__ lateral, const unsigned char* __restrict__ dl,
    uint32_t* __restrict__ ctr, uint32_t* __restrict__ flg,
    double* __restrict__ hnb, double* __restrict__ ypb,
    float* __restrict__ out)
{
  extern __shared__ double smd[];
  double* hist  = smd;                   // 32*513
  double* curr  = hist + 32*513;         // 256
  double* lastv = curr + 256;            // 256
  double* ypq   = lastv + 256;           // 1024
  double* hdels = ypq + 1024;            // 64
  double* redv  = hdels + 64;            // 4
  float*  effbs = (float*)(redv + 4);    // 256 f32
  int*    redi  = (int*)(effbs + 256);   // 4
  int*    misc  = redi + 4;              // 4

  const int tid = threadIdx.x;
  const int b   = blockIdx.x & 7;
  const int hc  = blockIdx.x >> 3;
  const int hl  = tid >> 4;              // local h 0..63
  const int p   = tid & 15;              // 16 lanes per h
  const int h   = hc * HSL + hl;

  // persistent regs: masked f32 weights + delays for i = p + 16k (strided)
  float w[32]; uint32_t dpk[8]; float aw[16];
  #pragma unroll
  for (int k = 0; k < 32; ++k){
    const int idx = h*HH + p + 16*k;
    const int d = (int)dl[idx];
    w[k] = (d >= 1) ? lateral[idx] : 0.0f;
    dpk[k >> 2] = (k & 3) ? (dpk[k >> 2] | ((uint32_t)d << ((k & 3)*8)))
                          : (uint32_t)d;
  }
  #pragma unroll
  for (int m = 0; m < 16; ++m) aw[m] = aff_w[(p + 16*m)*HH + h];
  const double ab = (double)aff_b[h];

  for (int q = tid; q < 32*513; q += NTHR) hist[q] = 0.0;
  if (tid < VV) effbs[tid] = eff_b[tid];
  __syncthreads();

  const int L = lengths[b];
  uint32_t* bctr = ctr + b*16;
  uint32_t* gctr = ctr + 128;
  uint32_t be = 0, ge = 0;
  int t = 0, stepc = 0;

  auto barrier = [&](uint32_t* c, uint32_t target){
    __syncthreads();
    if (tid == 0){
      __threadfence();
      __hip_atomic_fetch_add(c, 1u, __ATOMIC_RELEASE, __HIP_MEMORY_SCOPE_AGENT);
      while (__hip_atomic_load(c, __ATOMIC_ACQUIRE, __HIP_MEMORY_SCOPE_AGENT) < target) { }
      __threadfence();
    }
    __syncthreads();
  };

  auto gather = [&](double &hd, double &af){
    const int tm = t & 31;
    double a0 = 0.0, a1 = 0.0;
    #pragma unroll
    for (int k = 0; k < 32; ++k){
      const int d = (int)((dpk[k >> 2] >> ((k & 3)*8)) & 0xFFu);
      const int row = (tm - d) & 31;
      a0 += (double)w[k] * hist[row*513 + p + 16*k];
    }
    #pragma unroll
    for (int m = 0; m < 16; ++m) a1 += (double)aw[m] * curr[p + 16*m];
    #pragma unroll
    for (int m = 1; m < 16; m <<= 1){
      a0 += __shfl_xor(a0, m, 64);
      a1 += __shfl_xor(a1, m, 64);
    }
    hd = a0; af = a1;
  };

  auto ypartial = [&](){
    const int q = tid >> 8, v = tid & 255;
    double acc = 0.0;
    #pragma unroll
    for (int m = 0; m < 16; ++m)
      acc += hdels[q*16 + m] * (double)eff_w[(hc*HSL + q*16 + m)*VV + v];
    ypq[q*256 + v] = acc;
  };

  auto argmax256 = [&](double pr){
    if (tid < VV){
      double bv = pr; int bi = tid;
      #pragma unroll
      for (int m = 1; m < 64; m <<= 1){
        const double ov = __shfl_xor(bv, m, 64);
        const int    oi = __shfl_xor(bi, m, 64);
        if (ov > bv || (ov == bv && oi < bi)){ bv = ov; bi = oi; }
      }
      if ((tid & 63) == 0){ redv[tid >> 6] = bv; redi[tid >> 6] = bi; }
    }
    __syncthreads();
    if (tid == 0){
      double bv = redv[0]; int bi = redi[0];
      #pragma unroll
      for (int q2 = 1; q2 < 4; ++q2)
        if (redv[q2] > bv || (redv[q2] == bv && redi[q2] < bi)){ bv = redv[q2]; bi = redi[q2]; }
      misc[0] = bi;
    }
    __syncthreads();
  };

  // gumbel term log(-log(u)) in f64; u per jax uniform(minval=tiny), partitionable bits
  auto gumbel_t = [&](uint32_t base, int sv) -> double {
    uint32_t k0, k1; threefry(0u, 42u, 0u, base + (uint32_t)sv, k0, k1); // fold_in
    const uint32_t f = (uint32_t)(b*VV + tid);
    float u = bits_to_unit(pbits(k0, k1, f));
    if (u < 1.1754944e-38f) u = 1.1754944e-38f;
    return log(-log((double)u));
  };

  // ================= ENCODER =================
  for (; t < L; ){
    if (tid < IDIM) curr[tid] = (double)x[(b*TT + t)*IDIM + tid];
    __syncthreads();
    double hd, af; gather(hd, af);
    const double hn = tanh(hd + af + ab);
    const int par = stepc & 1;
    if (p == 0) astd(hnb + (par*NB + b)*HH + h, hn);
    ++be; barrier(bctr, 8u*be);
    if (tid < HH) hist[(t & 31)*513 + tid] = aldd(hnb + (par*NB + b)*HH + tid);
    ++t; ++stepc;
  }

  // ================= THINK =================
  if (tid < IDIM){
    const double xv = (double)x[(b*TT + (L-1))*IDIM + tid];
    curr[tid] = xv; lastv[tid] = xv;
  }
  __syncthreads();

  bool done = false; int tst = 0;
  for (int s = 0; s < NTHINK; ++s){
    double hd, af; gather(hd, af);
    const double hn = tanh(hd + af + ab);
    const int par = stepc & 1;
    const int sf  = s & 1;
    if (p == 0){ astd(hnb + (par*NB + b)*HH + h, hn); hdels[hl] = hd; }
    if (hc == 0 && tid == 0) astu(flg + sf*NB + b, done ? 1u : 0u);
    __syncthreads();
    ypartial();
    __syncthreads();
    if (tid < VV)
      astd(ypb + ((par*NB + b)*HCB + hc)*VV + tid,
           ypq[tid] + ypq[256 + tid] + ypq[512 + tid] + ypq[768 + tid]);
    ++ge; barrier(gctr, 64u*ge);
    if (tid == 0){
      uint32_t ad = 1u;
      #pragma unroll
      for (int bb = 0; bb < NB; ++bb) ad &= aldu(flg + sf*NB + bb);
      misc[1] = (int)ad;
    }
    __syncthreads();
    if (misc[1]) break;   // all done at step start: freeze (no commits)
    if (tid < HH) hist[(t & 31)*513 + tid] = aldd(hnb + (par*NB + b)*HH + tid);
    double yv = 0.0, pr = 0.0;
    if (tid < VV){
      double acc = (double)effbs[tid];
      #pragma unroll
      for (int c2 = 0; c2 < HCB; ++c2)
        acc += aldd(ypb + ((par*NB + b)*HCB + c2)*VV + tid);
      yv = acc;
      pr = yv - gumbel_t(1000u, s);
    }
    argmax256(pr);
    const int sampled = misc[0];
    const bool just = (sampled == VV - 1) && !done;
    if (!done){
      ++tst;
      if (tid < VV) lastv[tid] = yv;
    }
    const bool nd = done || just;
    if (tid < VV) curr[tid] = nd ? 0.0 : yv;
    done = nd;
    ++t; ++stepc;
    __syncthreads();
  }

  // ================= DECODE =================
  if (tid < VV) curr[tid] = lastv[tid];
  __syncthreads();
  for (int dj = 0; dj < NDEC; ++dj){
    double hd, af; gather(hd, af);
    const double hn = tanh(hd + af + ab);
    const int par = stepc & 1;
    if (p == 0){ astd(hnb + (par*NB + b)*HH + h, hn); hdels[hl] = hd; }
    __syncthreads();
    ypartial();
    __syncthreads();
    if (tid < VV)
      astd(ypb + ((par*NB + b)*HCB + hc)*VV + tid,
           ypq[tid] + ypq[256 + tid] + ypq[512 + tid] + ypq[768 + tid]);
    ++be; barrier(bctr, 8u*be);
    if (tid < HH) hist[(t & 31)*513 + tid] = aldd(hnb + (par*NB + b)*HH + tid);
    double yv = 0.0, pr = 0.0;
    if (tid < VV){
      double acc = (double)effbs[tid];
      #pragma unroll
      for (int c2 = 0; c2 < HCB; ++c2)
        acc += aldd(ypb + ((par*NB + b)*HCB + c2)*VV + tid);
      yv = acc;
      if (hc == 0 && tid < VV - 1)
        out[(b*NDEC + dj)*(VV - 1) + tid] = (float)yv;   // raw logits
      pr = yv - gumbel_t(2000u, dj);
    }
    argmax256(pr);
    const int sampled = misc[0];
    if (tid < VV) curr[tid] = (tid == sampled) ? 1.0 : 0.0;  // straight-through
    ++t; ++stepc;
    __syncthreads();
  }
  if (hc == 0 && tid == 0) out[NB*NDEC*(VV-1) + b] = (float)tst;
}

// ---------------- launcher ----------------
extern "C" void kernel_launch(void* const* d_in, const int* in_sizes, int n_in,
                              void* d_out, int out_size, void* d_ws, size_t ws_size,
                              hipStream_t stream)
{
  (void)in_sizes; (void)n_in; (void)out_size; (void)ws_size;
  const float* x     = (const float*)d_in[0];
  const int*   len   = (const int*)  d_in[1];
  const float* affw  = (const float*)d_in[2];
  const float* affb  = (const float*)d_in[3];
  const float* later = (const float*)d_in[4];
  const float* effw  = (const float*)d_in[5];
  const float* effb  = (const float*)d_in[6];
  const float* tau   = (const float*)d_in[7];

  char* ws = (char*)d_ws;
  uint32_t* ctr      = (uint32_t*)(ws + CTR_OFF);
  uint32_t* flg      = (uint32_t*)(ws + FLG_OFF);
  double* hnb        = (double*)(ws + HNEW_OFF);
  double* ypb        = (double*)(ws + YP_OFF);
  unsigned char* dl  = (unsigned char*)(ws + DLY_OFF);

  hipMemsetAsync(ctr, 0, 1024, stream);
  delays_kernel<<<dim3((HH*HH)/256), dim3(256), 0, stream>>>(tau, dl);

  const int smem = (32*513 + 256 + 256 + 1024 + 64 + 4) * 8 + 256*4 + 64;
  hipFuncSetAttribute((const void*)seq_kernel,
                      hipFuncAttributeMaxDynamicSharedMemorySize, smem);
  seq_kernel<<<dim3(64), dim3(NTHR), smem, stream>>>(
      x, len, affw, affb, effw, effb, later, dl, ctr, flg, hnb, ypb,
      (float*)d_out);
}

// Round 7
// 3601.823 us; speedup vs baseline: 1.3623x; 1.3623x over previous
//
#include <hip/hip_runtime.h>
#include <hip/hip_bf16.h>
#include <stdint.h>
#include <stddef.h>

// ---- problem constants ----
#define NB 8
#define TT 256
#define IDIM 256
#define HH 512
#define VV 256
#define DD 32
#define NDEC 64
#define NTHINK 16
#define HCB 8
#define HSL 64
#define NTHR 1024

// ---- ws layout (bytes), 8B aligned ----
#define HEX_OFF 0u        // [2][NB][HH]  u64 = 65,536
#define YEX_OFF 65536u    // [2][NB][HCB][VV] u64 = 262,144
#define FEX_OFF 327680u   // [NTHINK][NB] u64 = 1,024
#define DLY_OFF 328704u   // 512*512 u8 = 262,144 -> end 590,848
#define EXZ_BYTES 328704u // memset span (hex+yex+fex)

// ---------------- stamped exchange: (stamp<<32 | f32bits), fence-free ------
__device__ __forceinline__ void pubf(uint64_t* p, float v, uint32_t stamp){
  const uint64_t pk = ((uint64_t)stamp << 32) | (uint64_t)__float_as_uint(v);
  __hip_atomic_store(p, pk, __ATOMIC_RELAXED, __HIP_MEMORY_SCOPE_AGENT);
}
__device__ __forceinline__ float waitf(uint64_t* p, uint32_t stamp){
  uint64_t pk;
  do { pk = __hip_atomic_load(p, __ATOMIC_RELAXED, __HIP_MEMORY_SCOPE_AGENT); }
  while ((uint32_t)(pk >> 32) != stamp);
  return __uint_as_float((uint32_t)pk);
}

// ---------------- threefry2x32 (matches jax) ----------------
__device__ __forceinline__ void tfr(uint32_t &x0, uint32_t &x1, int r){
  x0 += x1; x1 = (x1 << r) | (x1 >> (32 - r)); x1 ^= x0;
}
__device__ __forceinline__ void threefry(uint32_t k0, uint32_t k1,
                                         uint32_t c0, uint32_t c1,
                                         uint32_t &o0, uint32_t &o1){
  const uint32_t k2 = k0 ^ k1 ^ 0x1BD11BDAu;
  uint32_t x0 = c0 + k0, x1 = c1 + k1;
  tfr(x0,x1,13); tfr(x0,x1,15); tfr(x0,x1,26); tfr(x0,x1,6);
  x0 += k1; x1 += k2 + 1u;
  tfr(x0,x1,17); tfr(x0,x1,29); tfr(x0,x1,16); tfr(x0,x1,24);
  x0 += k2; x1 += k0 + 2u;
  tfr(x0,x1,13); tfr(x0,x1,15); tfr(x0,x1,26); tfr(x0,x1,6);
  x0 += k0; x1 += k1 + 3u;
  tfr(x0,x1,17); tfr(x0,x1,29); tfr(x0,x1,16); tfr(x0,x1,24);
  x0 += k1; x1 += k2 + 4u;
  tfr(x0,x1,13); tfr(x0,x1,15); tfr(x0,x1,26); tfr(x0,x1,6);
  x0 += k2; x1 += k0 + 5u;
  o0 = x0; o1 = x1;
}
// jax partitionable threefry random_bits (32-bit): counter (0, i), bits = o0^o1
__device__ __forceinline__ uint32_t pbits(uint32_t k0, uint32_t k1, uint32_t i){
  uint32_t o0, o1; threefry(k0, k1, 0u, i, o0, o1);
  return o0 ^ o1;
}
__device__ __forceinline__ float bits_to_unit(uint32_t bits){
  return __uint_as_float((bits >> 9) | 0x3F800000u) - 1.0f;
}

// ---------------- kernel A: credit argmax -> delay table (0 = dead) --------
__global__ __launch_bounds__(256) void delays_kernel(
    const float* __restrict__ tau, unsigned char* __restrict__ dl)
{
  const int e = blockIdx.x * 256 + threadIdx.x;
  if (e >= HH*HH) return;
  uint32_t kc0, kc1; threefry(0u, 42u, 0u, 0u, kc0, kc1);  // fold_in(key(42),0)
  const float tcf = fminf(fmaxf(tau[e], 1.0f), 32.0f);
  const double tc = (double)tcf;
  double best = -1.0e300; int am = 0;
  for (int d = 0; d <= DD; ++d){
    const uint32_t f = (uint32_t)d * (uint32_t)(HH*HH) + (uint32_t)e;
    const double u = (double)bits_to_unit(pbits(kc0, kc1, f));
    const double raw = 1.0 / sqrt(1.0 + fabs((double)d - tc));
    const double pert = log(raw + 1e-8) - log(-log(u + 1e-8) + 1e-8);
    if (pert > best){ best = pert; am = d; }
  }
  dl[e] = (unsigned char)am;
}

// ---------------- kernel B: the sequential RNN -------------
__global__ __launch_bounds__(NTHR) void seq_kernel(
    const float* __restrict__ x, const int* __restrict__ lengths,
    const float* __restrict__ aff_w, const float* __restrict__ aff_b,
    const float* __restrict__ eff_w, const float* __restrict__ eff_b,
    const float* __restrict__ lateral, const unsigned char* __restrict__ dl,
    uint64_t* __restrict__ hex_, uint64_t* __restrict__ yex,
    uint64_t* __restrict__ fex, float* __restrict__ out)
{
  extern __shared__ double smd[];
  double* curr  = smd;                      // 256
  double* lastv = curr + 256;               // 256
  double* ypq   = lastv + 256;              // 1024
  double* hdels = ypq + 1024;               // 64
  double* redv  = hdels + 64;               // 4
  float*  hist  = (float*)(redv + 4);       // 32*513 f32
  float*  effs  = hist + 32*513;            // 64*256 f32
  float*  effbs = effs + 64*256;            // 256 f32
  int*    redi  = (int*)(effbs + 256);      // 4
  int*    misc  = redi + 4;                 // 16

  const int tid = threadIdx.x;
  const int b   = blockIdx.x & 7;
  const int hc  = blockIdx.x >> 3;
  const int hl  = tid >> 4;                 // local h 0..63
  const int p   = tid & 15;                 // 16 lanes per h
  const int h   = hc * HSL + hl;

  // persistent regs: masked f32 weights + delays for i = p + 16k (strided)
  float w[32]; uint32_t dpk[8]; float aw[16];
  #pragma unroll
  for (int k = 0; k < 32; ++k){
    const int idx = h*HH + p + 16*k;
    const int d = (int)dl[idx];
    w[k] = (d >= 1) ? lateral[idx] : 0.0f;
    dpk[k >> 2] = (k & 3) ? (dpk[k >> 2] | ((uint32_t)d << ((k & 3)*8)))
                          : (uint32_t)d;
  }
  #pragma unroll
  for (int m = 0; m < 16; ++m) aw[m] = aff_w[(p + 16*m)*HH + h];
  const double ab = (double)aff_b[h];

  for (int q = tid; q < 32*513; q += NTHR) hist[q] = 0.0f;
  for (int q = tid; q < HSL*VV; q += NTHR) effs[q] = eff_w[hc*HSL*VV + q];
  if (tid < VV) effbs[tid] = eff_b[tid];
  __syncthreads();

  const int L = lengths[b];
  int t = 0;               // committed steps (hist ring row)
  uint32_t stamp = 0;      // incremented on EVERY publish round

  auto gather = [&](double &hd, double &af){
    const int tm = t & 31;
    double a0 = 0.0, a1 = 0.0;
    #pragma unroll
    for (int k = 0; k < 32; ++k){
      const int d = (int)((dpk[k >> 2] >> ((k & 3)*8)) & 0xFFu);
      const int row = (tm - d) & 31;
      a0 += (double)w[k] * (double)hist[row*513 + p + 16*k];
    }
    #pragma unroll
    for (int m = 0; m < 16; ++m) a1 += (double)aw[m] * curr[p + 16*m];
    #pragma unroll
    for (int m = 1; m < 16; m <<= 1){
      a0 += __shfl_xor(a0, m, 64);
      a1 += __shfl_xor(a1, m, 64);
    }
    hd = a0; af = a1;
  };

  auto ypartial = [&](){
    const int q = tid >> 8, v = tid & 255;
    double acc = 0.0;
    #pragma unroll
    for (int m = 0; m < 16; ++m)
      acc += hdels[q*16 + m] * (double)effs[(q*16 + m)*VV + v];
    ypq[q*256 + v] = acc;
  };

  auto argmax256 = [&](double pr){
    if (tid < VV){
      double bv = pr; int bi = tid;
      #pragma unroll
      for (int m = 1; m < 64; m <<= 1){
        const double ov = __shfl_xor(bv, m, 64);
        const int    oi = __shfl_xor(bi, m, 64);
        if (ov > bv || (ov == bv && oi < bi)){ bv = ov; bi = oi; }
      }
      if ((tid & 63) == 0){ redv[tid >> 6] = bv; redi[tid >> 6] = bi; }
    }
    __syncthreads();
    if (tid == 0){
      double bv = redv[0]; int bi = redi[0];
      #pragma unroll
      for (int q2 = 1; q2 < 4; ++q2)
        if (redv[q2] > bv || (redv[q2] == bv && redi[q2] < bi)){ bv = redv[q2]; bi = redi[q2]; }
      misc[0] = bi;
    }
    __syncthreads();
  };

  auto gumbel_t = [&](uint32_t base, int sv) -> double {
    uint32_t k0, k1; threefry(0u, 42u, 0u, base + (uint32_t)sv, k0, k1); // fold_in
    const uint32_t f = (uint32_t)(b*VV + tid);
    float u = bits_to_unit(pbits(k0, k1, f));
    if (u < 1.1754944e-38f) u = 1.1754944e-38f;
    return log(-log((double)u));
  };

  // ================= ENCODER =================
  for (; t < L; ){
    if (tid < IDIM) curr[tid] = (double)x[(b*TT + t)*IDIM + tid];
    __syncthreads();                         // covers prev hist write too
    double hd, af; gather(hd, af);
    const double hn = tanh(hd + af + ab);
    const uint32_t stp = ++stamp;
    const int par = (int)(stp & 1u);
    uint64_t* slab = hex_ + (par*NB + b)*HH;
    if (p == 0) pubf(slab + h, (float)hn, stp);
    if (tid < HH) hist[(t & 31)*513 + tid] = waitf(slab + tid, stp);
    ++t;
  }

  // ================= THINK =================
  if (tid < IDIM){
    const double xv = (double)x[(b*TT + (L-1))*IDIM + tid];
    curr[tid] = xv; lastv[tid] = xv;
  }
  __syncthreads();

  bool done = false; int tst = 0;
  for (int s = 0; s < NTHINK; ++s){
    double hd, af; gather(hd, af);
    const double hn = tanh(hd + af + ab);
    const uint32_t stp = ++stamp;
    const int par = (int)(stp & 1u);
    uint64_t* slab = hex_ + (par*NB + b)*HH;
    uint64_t* yslab = yex + ((par*NB + b)*HCB)*VV;
    if (p == 0){ pubf(slab + h, (float)hn, stp); hdels[hl] = hd; }
    if (hc == 0 && tid == 0)
      __hip_atomic_store(fex + s*NB + b, (uint64_t)(done ? 2u : 1u),
                         __ATOMIC_RELAXED, __HIP_MEMORY_SCOPE_AGENT);
    __syncthreads();
    ypartial();
    __syncthreads();
    if (tid < VV)
      pubf(yslab + hc*VV + tid,
           (float)(ypq[tid] + ypq[256 + tid] + ypq[512 + tid] + ypq[768 + tid]), stp);
    // all-done-at-step-start check (cross-batch)
    if (tid < NB){
      uint64_t v;
      do { v = __hip_atomic_load(fex + s*NB + tid, __ATOMIC_RELAXED,
                                 __HIP_MEMORY_SCOPE_AGENT); } while (v == 0ull);
      misc[2 + tid] = (v == 2ull);
    }
    __syncthreads();
    if (tid == 0){
      int ad = 1;
      #pragma unroll
      for (int bb = 0; bb < NB; ++bb) ad &= misc[2 + bb];
      misc[1] = ad;
    }
    __syncthreads();
    if (misc[1]) break;                       // freeze: nothing consumed
    if (tid < HH) hist[(t & 31)*513 + tid] = waitf(slab + tid, stp);
    double yv = 0.0, pr = 0.0;
    if (tid < VV){
      double acc = (double)effbs[tid];
      float part[8]; uint32_t need = 0xFFu;
      while (need){
        #pragma unroll
        for (int c = 0; c < HCB; ++c) if (need & (1u << c)){
          const uint64_t pk = __hip_atomic_load(yslab + c*VV + tid,
                              __ATOMIC_RELAXED, __HIP_MEMORY_SCOPE_AGENT);
          if ((uint32_t)(pk >> 32) == stp){
            part[c] = __uint_as_float((uint32_t)pk); need &= ~(1u << c);
          }
        }
      }
      #pragma unroll
      for (int c = 0; c < HCB; ++c) acc += (double)part[c];
      yv = acc;
      pr = yv - gumbel_t(1000u, s);
    }
    argmax256(pr);
    const int sampled = misc[0];
    const bool just = (sampled == VV - 1) && !done;
    if (!done){
      ++tst;
      if (tid < VV) lastv[tid] = yv;
    }
    const bool nd = done || just;
    if (tid < VV) curr[tid] = nd ? 0.0 : yv;
    done = nd;
    ++t;
    __syncthreads();
  }

  // ================= DECODE =================
  if (tid < VV) curr[tid] = lastv[tid];
  __syncthreads();
  for (int dj = 0; dj < NDEC; ++dj){
    double hd, af; gather(hd, af);
    const double hn = tanh(hd + af + ab);
    const uint32_t stp = ++stamp;
    const int par = (int)(stp & 1u);
    uint64_t* slab = hex_ + (par*NB + b)*HH;
    uint64_t* yslab = yex + ((par*NB + b)*HCB)*VV;
    if (p == 0){ pubf(slab + h, (float)hn, stp); hdels[hl] = hd; }
    __syncthreads();
    ypartial();
    __syncthreads();
    if (tid < VV)
      pubf(yslab + hc*VV + tid,
           (float)(ypq[tid] + ypq[256 + tid] + ypq[512 + tid] + ypq[768 + tid]), stp);
    if (tid < HH) hist[(t & 31)*513 + tid] = waitf(slab + tid, stp);
    double yv = 0.0, pr = 0.0;
    if (tid < VV){
      double acc = (double)effbs[tid];
      float part[8]; uint32_t need = 0xFFu;
      while (need){
        #pragma unroll
        for (int c = 0; c < HCB; ++c) if (need & (1u << c)){
          const uint64_t pk = __hip_atomic_load(yslab + c*VV + tid,
                              __ATOMIC_RELAXED, __HIP_MEMORY_SCOPE_AGENT);
          if ((uint32_t)(pk >> 32) == stp){
            part[c] = __uint_as_float((uint32_t)pk); need &= ~(1u << c);
          }
        }
      }
      #pragma unroll
      for (int c = 0; c < HCB; ++c) acc += (double)part[c];
      yv = acc;
      if (hc == 0 && tid < VV - 1)
        out[(b*NDEC + dj)*(VV - 1) + tid] = (float)yv;   // raw logits
      pr = yv - gumbel_t(2000u, dj);
    }
    argmax256(pr);
    const int sampled = misc[0];
    if (tid < VV) curr[tid] = (tid == sampled) ? 1.0 : 0.0;  // straight-through
    ++t;
    __syncthreads();
  }
  if (hc == 0 && tid == 0) out[NB*NDEC*(VV-1) + b] = (float)tst;
}

// ---------------- launcher ----------------
extern "C" void kernel_launch(void* const* d_in, const int* in_sizes, int n_in,
                              void* d_out, int out_size, void* d_ws, size_t ws_size,
                              hipStream_t stream)
{
  (void)in_sizes; (void)n_in; (void)out_size; (void)ws_size;
  const float* x     = (const float*)d_in[0];
  const int*   len   = (const int*)  d_in[1];
  const float* affw  = (const float*)d_in[2];
  const float* affb  = (const float*)d_in[3];
  const float* later = (const float*)d_in[4];
  const float* effw  = (const float*)d_in[5];
  const float* effb  = (const float*)d_in[6];
  const float* tau   = (const float*)d_in[7];

  char* ws = (char*)d_ws;
  uint64_t* hex_     = (uint64_t*)(ws + HEX_OFF);
  uint64_t* yex      = (uint64_t*)(ws + YEX_OFF);
  uint64_t* fex      = (uint64_t*)(ws + FEX_OFF);
  unsigned char* dl  = (unsigned char*)(ws + DLY_OFF);

  hipMemsetAsync(ws, 0, EXZ_BYTES, stream);   // reset stamps each launch/replay
  delays_kernel<<<dim3((HH*HH)/256), dim3(256), 0, stream>>>(tau, dl);

  const int smem = (256 + 256 + 1024 + 64 + 4) * 8
                 + (32*513 + 64*256 + 256) * 4 + 20 * 4;
  hipFuncSetAttribute((const void*)seq_kernel,
                      hipFuncAttributeMaxDynamicSharedMemorySize, smem);
  seq_kernel<<<dim3(64), dim3(NTHR), smem, stream>>>(
      x, len, affw, affb, effw, effb, later, dl, hex_, yex, fex,
      (float*)d_out);
}